// Round 7
// baseline (123.362 us; speedup 1.0000x reference)
//
#include <hip/hip_runtime.h>

// Problem constants (fixed by the reference setup)
#define BB   2
#define DD   96
#define HH   96
#define WW   96
#define CINC 16
#define COUTC 32
#define KVOL 27
#define GRID_VOX (BB*DD*HH*WW)         // 1,769,472 voxels
#define NW (KVOL*CINC*COUTC)           // 13824 weights
#define VPT 8                          // voxels per thread in compact
#define CVB (256*VPT)                  // voxels per compact block = 2048
#define SWP 20                         // LDS B-row pitch in halfs (40 B):
                                       // start bank 10*co mod 32 -> 2-way = free

typedef _Float16 half4 __attribute__((ext_vector_type(4)));
typedef _Float16 half8 __attribute__((ext_vector_type(8)));
typedef float    floatx16 __attribute__((ext_vector_type(16)));

// ---------------- dispatch 1: scatter pids + repack weights + zero counter ---
// Weights repacked to f16 B-operand layout: wH[kk][co][ci] (ci contiguous).
__global__ __launch_bounds__(256) void setup_kernel(
        const int* __restrict__ idx, int* __restrict__ g,
        const float* __restrict__ w, _Float16* __restrict__ wH,
        int* __restrict__ counter, int n, int scatter_blocks) {
    if ((int)blockIdx.x < scatter_blocks) {
        int i = blockIdx.x * 256 + threadIdx.x;
        if (i >= n) return;
        int4 v = ((const int4*)idx)[i];   // (b, z, y, x)
        int lin = ((v.x * DD + v.y) * HH + v.z) * WW + v.w;
        g[lin] = i;
    } else {
        int t = ((int)blockIdx.x - scatter_blocks) * 256 + threadIdx.x;
        if (t == 0) counter[0] = 0;
        if (t >= NW) return;              // t = kk*512 + co*16 + ci
        int ci = t & (CINC - 1);
        int co = (t >> 4) & (COUTC - 1);
        int kk = t >> 9;
        wH[t] = (_Float16)w[(co * CINC + ci) * KVOL + kk];
    }
}

// -------- dispatch 2: block-ordered compaction + in-place grid rewrite -------
// After: g[v] = sorted id j for active voxels, n for empty. featH[j] (f16) =
// feat[perm[j]]; pc[j] = packed coords; featH[n] = zero row.
// NO grid pre-init needed: entry accepted only if pid<n AND idx[pid]
// round-trips to this voxel — correct under arbitrary initial grid garbage.
__global__ __launch_bounds__(256) void compact_kernel(
        const int* __restrict__ idx, const float* __restrict__ feat,
        int* __restrict__ g, _Float16* __restrict__ featH,
        int* __restrict__ pc, int* __restrict__ perm,
        int* __restrict__ counter, int n) {
    __shared__ int s_wsum[4];
    __shared__ int s_wbase[4];
    __shared__ int s_base;
    const int t = threadIdx.x;
    const int lane = t & 63;
    const int wv = t >> 6;
    const int base = blockIdx.x * CVB + t * VPT;

    int4 a0 = ((const int4*)(g + base))[0];
    int4 a1 = ((const int4*)(g + base))[1];
    int vals[VPT] = {a0.x, a0.y, a0.z, a0.w, a1.x, a1.y, a1.z, a1.w};
    int pid[VPT], pck[VPT];
    int cnt = 0;
#pragma unroll
    for (int q = 0; q < VPT; ++q) {       // fully unrolled: static indices only
        int p = vals[q];
        bool ok = ((unsigned)p < (unsigned)n);
        int pk = 0;
        if (ok) {
            int4 c = ((const int4*)idx)[p];
            int lin = ((c.x * DD + c.y) * HH + c.z) * WW + c.w;
            ok = (lin == base + q);
            pk = (c.x << 21) | (c.y << 14) | (c.z << 7) | c.w;
        }
        pid[q] = ok ? p : -1;
        pck[q] = pk;
        cnt += ok ? 1 : 0;
    }

    // wave-level inclusive scan (shfl), then tiny cross-wave combine
    int incl = cnt;
#pragma unroll
    for (int d = 1; d < 64; d <<= 1) {
        int v = __shfl_up(incl, d);
        if (lane >= d) incl += v;
    }
    if (lane == 63) s_wsum[wv] = incl;
    __syncthreads();
    if (t == 0) {
        int t0 = s_wsum[0], t1 = s_wsum[1], t2 = s_wsum[2], t3 = s_wsum[3];
        s_wbase[0] = 0; s_wbase[1] = t0; s_wbase[2] = t0 + t1;
        s_wbase[3] = t0 + t1 + t2;
        s_base = atomicAdd(counter, t0 + t1 + t2 + t3);
    }
    __syncthreads();
    int o = s_base + s_wbase[wv] + incl - cnt;

#pragma unroll
    for (int q = 0; q < VPT; ++q) {
        int tag = n;                      // empty marker -> zero row
        int p = pid[q];
        if (p >= 0) {
            pc[o] = pck[q];
            perm[o] = p;
            const float4* src = (const float4*)(feat + (size_t)p * CINC);
            float4 f0 = src[0], f1 = src[1], f2 = src[2], f3 = src[3];
            half8 h0, h1;
            h0[0]=(_Float16)f0.x; h0[1]=(_Float16)f0.y; h0[2]=(_Float16)f0.z; h0[3]=(_Float16)f0.w;
            h0[4]=(_Float16)f1.x; h0[5]=(_Float16)f1.y; h0[6]=(_Float16)f1.z; h0[7]=(_Float16)f1.w;
            h1[0]=(_Float16)f2.x; h1[1]=(_Float16)f2.y; h1[2]=(_Float16)f2.z; h1[3]=(_Float16)f2.w;
            h1[4]=(_Float16)f3.x; h1[5]=(_Float16)f3.y; h1[6]=(_Float16)f3.z; h1[7]=(_Float16)f3.w;
            half8* dst = (half8*)(featH + (size_t)o * CINC);
            dst[0] = h0; dst[1] = h1;
            tag = o;
            ++o;
        }
        g[base + q] = tag;
    }
    if (blockIdx.x == 0 && t == 0) {      // zero row at featH[n]
        half8* zr = (half8*)(featH + (size_t)n * CINC);
        half8 hz = {};
        zr[0] = hz; zr[1] = hz;
    }
}

// ------------------------------- dispatch 3: conv (implicit GEMM) -----------
// One wave = 32 sorted points x 32 couts; 27 MFMA (32x32x16 f16), K=CIN/tap.
// LDS B: 40B pitch (2-way bank = free), 34,560 B -> 4 blocks/CU.
// Dual accumulators halve the serial MFMA chain.
__global__ __launch_bounds__(256, 4) void conv_mfma_kernel(
        const _Float16* __restrict__ featH, const int* __restrict__ pc,
        const int* __restrict__ perm, const _Float16* __restrict__ wH,
        const float* __restrict__ bias, const int* __restrict__ g,
        float* __restrict__ out, int n) {
    __shared__ _Float16 sW[KVOL * 32 * SWP];   // 34,560 B
    const int lane = threadIdx.x & 63;
    const int wave = threadIdx.x >> 6;
    const int m    = lane & 31;           // point-in-tile (A) / cout (C cols)
    const int hf   = lane >> 5;           // k-half: channels hf*8..hf*8+7

    // Stage weights into LDS — ALL threads participate (barrier before exits).
    for (int u = threadIdx.x; u < KVOL * 64; u += 256) {
        int kk = u >> 6, r = u & 63;
        int co = r >> 1, h = r & 1;
        const half4* src = (const half4*)(wH + kk * (COUTC * CINC) + co * CINC + h * 8);
        half4 v0 = src[0], v1 = src[1];
        _Float16* dst = &sW[kk * 32 * SWP + co * SWP + h * 8];
        *(half4*)dst = v0;                 // 8B-aligned (40*co, 8*h)
        *(half4*)(dst + 4) = v1;
    }
    __syncthreads();

    const int j0 = (blockIdx.x * 4 + wave) * 32;
    if (j0 >= n) return;                  // no barriers after this point
    const int j = j0 + m;                 // j < n (n % 32 == 0)

    const int p = pc[j];
    const int x = p & 127, y = (p >> 7) & 127, z = (p >> 14) & 127, b = p >> 21;
    const int base = ((b * DD + z) * HH + y) * WW + x;
    const int pm = perm[j];               // original row for point m

    // Phase 1: probe all 27 neighbor ids (independent loads, static reg array)
    int nid[KVOL];
#pragma unroll
    for (int kk = 0; kk < KVOL; ++kk) {
        const int dz = kk / 9 - 1, dy = (kk / 3) % 3 - 1, dx = kk % 3 - 1;
        int nz = z + dz, ny = y + dy, nx = x + dx;
        bool inb = ((unsigned)nz < DD) & ((unsigned)ny < HH) & ((unsigned)nx < WW);
        int addr = inb ? base + (dz * HH + dy) * WW + dx : 0;
        int v = g[addr];
        nid[kk] = inb ? v : n;            // empty/OOB -> zero row
    }

    // Dual accumulators: even taps -> acc0 (bias-init), odd taps -> acc1 (0).
    float bval = bias[m];
    floatx16 acc0, acc1;
#pragma unroll
    for (int i = 0; i < 16; ++i) { acc0[i] = bval; acc1[i] = 0.0f; }

    // Phase 2: 3 groups x (9 batched A-gathers -> 9 LDS-B + MFMA)
#pragma unroll
    for (int gq = 0; gq < 3; ++gq) {
        half8 av[9];
#pragma unroll
        for (int q = 0; q < 9; ++q)
            av[q] = *(const half8*)(featH + (size_t)nid[gq * 9 + q] * CINC + hf * 8);
#pragma unroll
        for (int q = 0; q < 9; ++q) {
            const int kk = gq * 9 + q;
            const _Float16* bp = &sW[kk * 32 * SWP + m * SWP + hf * 8];
            half4 b0 = *(const half4*)bp;
            half4 b1 = *(const half4*)(bp + 4);
            half8 bf;
            bf[0]=b0[0]; bf[1]=b0[1]; bf[2]=b0[2]; bf[3]=b0[3];
            bf[4]=b1[0]; bf[5]=b1[1]; bf[6]=b1[2]; bf[7]=b1[3];
            if (kk & 1)
                acc1 = __builtin_amdgcn_mfma_f32_32x32x16_f16(av[q], bf, acc1, 0, 0, 0);
            else
                acc0 = __builtin_amdgcn_mfma_f32_32x32x16_f16(av[q], bf, acc0, 0, 0, 0);
        }
    }

    // Epilogue: reg i -> row r=(i&3)+8*(i>>2)+4*hf, col m. perm via shfl.
#pragma unroll
    for (int i = 0; i < 16; ++i) {
        int r = (i & 3) + 8 * (i >> 2) + 4 * hf;
        int row = __shfl(pm, r);          // lanes r and r+32 hold same pm
        out[(size_t)row * COUTC + m] = acc0[i] + acc1[i];  // one 128B row/reg
    }
}

extern "C" void kernel_launch(void* const* d_in, const int* in_sizes, int n_in,
                              void* d_out, int out_size, void* d_ws, size_t ws_size,
                              hipStream_t stream) {
    const float* feat  = (const float*)d_in[0];   // [N,16] fp32
    const int*   idx   = (const int*)d_in[1];     // [N,4]  int32
    const float* convw = (const float*)d_in[2];   // [32,16,3,3,3] fp32
    const float* convb = (const float*)d_in[3];   // [32] fp32
    float* out = (float*)d_out;

    const int n = in_sizes[1] / 4;                // 200000

    // workspace layout (all 16B-aligned)
    char* ws = (char*)d_ws;
    int*      g       = (int*)ws;                               // 7,077,888 B
    int*      counter = (int*)(ws + GRID_VOX * 4);              //       256 B pad
    int*      pc      = (int*)(ws + GRID_VOX * 4 + 256);        //   n*4 B
    int*      perm    = pc + n;                                 //   n*4 B
    _Float16* featH   = (_Float16*)(perm + n);                  // (n+1)*32 B
    _Float16* wH      = featH + (size_t)(n + 1) * CINC;         //  NW*2 B

    const int sb = (n + 255) / 256;
    const int rb = (NW + 255) / 256;
    setup_kernel<<<sb + rb, 256, 0, stream>>>(idx, g, convw, wH, counter, n, sb);
    compact_kernel<<<GRID_VOX / CVB, 256, 0, stream>>>(
        idx, feat, g, featH, pc, perm, counter, n);

    const int waves = (n + 31) / 32;              // 6250
    conv_mfma_kernel<<<(waves + 3) / 4, 256, 0, stream>>>(
        featH, pc, perm, wH, convb, g, out, n);
}